// Round 1
// 140.173 us; speedup vs baseline: 1.1070x; 1.1070x over previous
//
#include <hip/hip_runtime.h>
#include <hip/hip_bf16.h>
#include <math.h>

#define HID    128
#define BATCH  8192
#define NM     16
#define NROWS  (BATCH * NM)      // 131072
#define BN_EPS 1e-5f

#define S1_BLOCKS 256
#define S1_ROWS   (NROWS / S1_BLOCKS)   // 512

// workspace layout (floats)
#define WS_PS    0
#define WS_PQ    (S1_BLOCKS * HID)          // 32768
#define WS_SCALE (2 * S1_BLOCKS * HID)      // 65536
#define WS_SHIFT (WS_SCALE + HID)           // 65664
#define WS_BW    (WS_SHIFT + HID)           // 65792 floats -> bf16 weight region
// bf16 region (ushort): [0:16384) Wa1T block0, [16384:32768) Wa2T, [32768:65536) Wa1baseT

// output layout (floats)
#define O1 ((size_t)BATCH * NM)                 // h_pooled
#define O2 (O1 + (size_t)BATCH * HID)           // machine_v

#define G    4
#define ROWS (G * NM)   // 64 rows per main block
#define LDH  136        // padded bf16 row stride (272 B == 4 mod 32 banks)
#define ZLD  264        // z tile row stride (528 B == 4 mod 32 banks)

typedef __attribute__((ext_vector_type(8))) short short8_t;
typedef __attribute__((ext_vector_type(4))) float f32x4;

#define MFMA16(a, b, c) __builtin_amdgcn_mfma_f32_16x16x32_bf16(a, b, c, 0, 0, 0)

__device__ __forceinline__ unsigned short f2bf(float x) {
    __hip_bfloat16 h = __float2bfloat16(x);
    return *reinterpret_cast<unsigned short*>(&h);
}
__device__ __forceinline__ float ftanh(float x) {
    float e = __expf(2.0f * x);
    return 1.0f - 2.0f / (e + 1.0f);
}

// ---------------------------------------------------------------------------
// Kernel 1: per-block partial sums/sumsq of m_fea1 = fea1 @ W1 over rows
// ---------------------------------------------------------------------------
__global__ __launch_bounds__(256) void bn_stats_kernel(
    const float* __restrict__ fea1, const float* __restrict__ W1,
    float* __restrict__ ws)
{
    __shared__ float feaS[S1_ROWS * 6];
    __shared__ float w1S[6 * HID];
    __shared__ float redS[512];

    const int tid = threadIdx.x;
    const int blk = blockIdx.x;

    const float* src = fea1 + (size_t)blk * (S1_ROWS * 6);
    for (int i = tid; i < S1_ROWS * 6; i += 256) feaS[i] = src[i];
    for (int i = tid; i < 6 * HID; i += 256)     w1S[i]  = W1[i];
    __syncthreads();

    const int c = tid & 127;
    const int h = tid >> 7;

    float s = 0.f, q = 0.f;
    const int rbeg = h * (S1_ROWS / 2);
    for (int r = rbeg; r < rbeg + S1_ROWS / 2; ++r) {
        const float* fr = feaS + r * 6;
        float m = fr[0] * w1S[0 * HID + c] + fr[1] * w1S[1 * HID + c]
                + fr[2] * w1S[2 * HID + c] + fr[3] * w1S[3 * HID + c]
                + fr[4] * w1S[4 * HID + c] + fr[5] * w1S[5 * HID + c];
        s += m;
        q += m * m;
    }
    redS[tid] = s;
    __syncthreads();
    if (tid < 128) ws[WS_PS + blk * HID + tid] = redS[tid] + redS[tid + 128];
    __syncthreads();
    redS[tid] = q;
    __syncthreads();
    if (tid < 128) ws[WS_PQ + blk * HID + tid] = redS[tid] + redS[tid + 128];
}

// ---------------------------------------------------------------------------
// Kernel 2: reduce partials -> scale/shift per channel
// ---------------------------------------------------------------------------
__global__ __launch_bounds__(512) void bn_finalize_kernel(
    const float* __restrict__ gamma, const float* __restrict__ beta,
    float* __restrict__ ws)
{
    __shared__ float red[1024];
    const int tid = threadIdx.x;
    const int c  = tid & 127;
    const int pc = tid >> 7;

    float s = 0.f, q = 0.f;
    for (int p = pc * 64; p < pc * 64 + 64; ++p) {
        s += ws[WS_PS + p * HID + c];
        q += ws[WS_PQ + p * HID + c];
    }
    red[tid] = s;
    red[512 + tid] = q;
    __syncthreads();
    if (tid < 128) {
        float ss = red[tid] + red[tid + 128] + red[tid + 256] + red[tid + 384];
        float qq = red[512 + tid] + red[512 + tid + 128] + red[512 + tid + 256] + red[512 + tid + 384];
        const float inv = 1.0f / (float)NROWS;
        float mu  = ss * inv;
        float var = qq * inv - mu * mu;
        float sc  = gamma[tid] * rsqrtf(var + BN_EPS);
        ws[WS_SCALE + tid] = sc;
        ws[WS_SHIFT + tid] = beta[tid] - mu * sc;
    }
}

// ---------------------------------------------------------------------------
// Kernel 2b: convert weights to transposed bf16 [col][k] layouts
// ---------------------------------------------------------------------------
__global__ __launch_bounds__(256) void prep_kernel(
    const float* __restrict__ Wa1, const float* __restrict__ Wa2,
    unsigned short* __restrict__ wbt)
{
    const int idx = blockIdx.x * 256 + threadIdx.x;   // 0..32767
    if (idx < 16384) {
        const int c = idx >> 7, k = idx & 127;
        wbt[c * 128 + k]         = f2bf(Wa1[(size_t)k * HID + c]);   // rows 0..127
        wbt[16384 + c * 128 + k] = f2bf(Wa2[(size_t)k * HID + c]);
    }
    const int c = idx >> 8, k = idx & 255;
    wbt[32768 + c * 256 + k] = f2bf(Wa1[(size_t)(HID + k) * HID + c]);  // rows 128..383
}

// ---------------------------------------------------------------------------
// Kernel 3: fused main kernel, G=4 batch elements per block, MFMA GEMMs
// LDS cut 46.6KB -> ~31.1KB: GEMM1 writes x1 in place into hmS (wave-local
// rows), z tile gets its own small buffer. -> 5 blocks/CU instead of 3.
// ---------------------------------------------------------------------------
__global__ __launch_bounds__(256, 5) void main_kernel(
    const float* __restrict__ fea1, const float* __restrict__ hpo,
    const unsigned char* __restrict__ mask,
    const float* __restrict__ W1,
    const float* __restrict__ ba1, const float* __restrict__ ba2,
    const float* __restrict__ Wa3, const float* __restrict__ ba3,
    const float* __restrict__ Wc1, const float* __restrict__ bc1,
    const float* __restrict__ Wc2, const float* __restrict__ bc2,
    const float* __restrict__ Wc3, const float* __restrict__ bc3,
    const float* __restrict__ ws, const unsigned short* __restrict__ wbt,
    float* __restrict__ out)
{
    __shared__ __align__(16) unsigned short hmS[ROWS * LDH];  // 17408 B (hm, then x1 in place)
    __shared__ __align__(16) unsigned short zS[G * ZLD];      // 2112 B  (z tile for base GEMM)
    __shared__ float hpS[G * HID];                            // 2048 B
    __shared__ float baseS[G * HID];                          // 2048 B
    __shared__ float scaleS[HID], shiftS[HID];
    __shared__ float ba1S[HID], ba2S[HID], wa3S[HID];         // 2560 B total w/ above
    __shared__ float scS[ROWS];                               // 256 B
    __shared__ __align__(16) float regA[1152];                // 4608 B: feaS(384)+w1S(768); later v1S/v2S

    float* feaS = regA;
    float* w1S  = regA + 384;
    float* v1S  = regA;
    float* v2S  = regA + 512;

    const int tid = threadIdx.x;
    const int b0  = blockIdx.x * G;

    // ---- stage ----
    for (int i = tid; i < ROWS * 6; i += 256) feaS[i] = fea1[(size_t)b0 * (NM * 6) + i];
    for (int i = tid; i < 6 * HID; i += 256)  w1S[i]  = W1[i];
    if (tid < HID) {
        scaleS[tid] = ws[WS_SCALE + tid];
        shiftS[tid] = ws[WS_SHIFT + tid];
        ba1S[tid]   = ba1[tid];
        ba2S[tid]   = ba2[tid];
        wa3S[tid]   = Wa3[tid];
    }
    // hpo -> bf16 z tile (cols 128..255)
    for (int i = tid; i < G * HID; i += 256) {
        const int g = i >> 7, c = i & 127;
        zS[g * ZLD + 128 + c] = f2bf(hpo[(size_t)b0 * HID + i]);
    }
    __syncthreads();

    // ---- hm = BN(fea @ W1) -> bf16 LDS; h_pooled exact fp32 ----
    {
        const int c2 = tid & 63;   // col pair
        const int h  = tid >> 6;   // batch elem in block
        const int ca = 2 * c2, cb = 2 * c2 + 1;
        const float sc0 = scaleS[ca], sc1 = scaleS[cb];
        const float sh0 = shiftS[ca], sh1 = shiftS[cb];
        float s0 = 0.f, s1 = 0.f;
        for (int m = 0; m < NM; ++m) {
            const float* fr = feaS + (h * NM + m) * 6;
            float a0 = fr[0] * w1S[0 * HID + ca] + fr[1] * w1S[1 * HID + ca]
                     + fr[2] * w1S[2 * HID + ca] + fr[3] * w1S[3 * HID + ca]
                     + fr[4] * w1S[4 * HID + ca] + fr[5] * w1S[5 * HID + ca];
            float a1 = fr[0] * w1S[0 * HID + cb] + fr[1] * w1S[1 * HID + cb]
                     + fr[2] * w1S[2 * HID + cb] + fr[3] * w1S[3 * HID + cb]
                     + fr[4] * w1S[4 * HID + cb] + fr[5] * w1S[5 * HID + cb];
            a0 = a0 * sc0 + sh0;
            a1 = a1 * sc1 + sh1;
            s0 += a0; s1 += a1;
            ushort2 u; u.x = f2bf(a0); u.y = f2bf(a1);
            *(ushort2*)&hmS[(h * NM + m) * LDH + ca] = u;
        }
        s0 *= (1.0f / NM); s1 *= (1.0f / NM);
        hpS[h * HID + ca] = s0;
        hpS[h * HID + cb] = s1;
        float2 hv; hv.x = s0; hv.y = s1;
        *(float2*)(out + O1 + (size_t)(b0 + h) * HID + ca) = hv;
        ushort2 uz; uz.x = f2bf(s0); uz.y = f2bf(s1);
        *(ushort2*)&zS[h * ZLD + ca] = uz;   // z tile cols 0..127
    }
    __syncthreads();

    const int w    = tid >> 6;
    const int lane = tid & 63;
    const int lr   = lane & 15;
    const int lg   = lane >> 4;

    const unsigned short* wbt1 = wbt;
    const unsigned short* wbt2 = wbt + 16384;
    const unsigned short* wbtB = wbt + 32768;

    // ---- base = ba1 + z @ Wa1[128:384] via MFMA (rows 4..15 of A are don't-care;
    //      clamp lr&3 so all reads are in-bounds of the 4-row zS tile) ----
    {
        short8_t za[8];
        const unsigned short* zr = zS + (lr & 3) * ZLD + lg * 8;
        #pragma unroll
        for (int kk = 0; kk < 8; ++kk) za[kk] = *(const short8_t*)(zr + kk * 32);
        #pragma unroll
        for (int t = 0; t < 2; ++t) {
            const int n = 2 * w + t;
            const unsigned short* br = wbtB + (n * 16 + lr) * 256 + lg * 8;
            const float bi = ba1S[n * 16 + lr];
            f32x4 acc = {bi, bi, bi, bi};
            #pragma unroll
            for (int kk = 0; kk < 8; ++kk) {
                short8_t b = *(const short8_t*)(br + kk * 32);
                acc = MFMA16(za[kk], b, acc);
            }
            if (lg == 0) {
                #pragma unroll
                for (int i = 0; i < 4; ++i)
                    baseS[i * HID + n * 16 + lr] = acc[i];
            }
        }
    }
    __syncthreads();

    // ---- GEMM1: x1 = tanh(hm @ Wa1[0:128] + base) -> bf16, in place into hmS ----
    // Safe: wave w reads its rows w*16..w*16+15 into registers before writing
    // the same rows; rows are never touched by another wave.
    {
        short8_t ha[4];
        const unsigned short* ar = hmS + (w * 16 + lr) * LDH + lg * 8;
        #pragma unroll
        for (int kk = 0; kk < 4; ++kk) ha[kk] = *(const short8_t*)(ar + kk * 32);
        #pragma unroll
        for (int n = 0; n < 8; ++n) {
            const unsigned short* br = wbt1 + (n * 16 + lr) * 128 + lg * 8;
            short8_t b0 = *(const short8_t*)(br);
            short8_t b1 = *(const short8_t*)(br + 32);
            short8_t b2 = *(const short8_t*)(br + 64);
            short8_t b3 = *(const short8_t*)(br + 96);
            const float bi = baseS[w * HID + n * 16 + lr];
            f32x4 acc = {bi, bi, bi, bi};
            acc = MFMA16(ha[0], b0, acc);
            acc = MFMA16(ha[1], b1, acc);
            acc = MFMA16(ha[2], b2, acc);
            acc = MFMA16(ha[3], b3, acc);
            #pragma unroll
            for (int i = 0; i < 4; ++i)
                hmS[(w * 16 + lg * 4 + i) * LDH + n * 16 + lr] = f2bf(ftanh(acc[i]));
        }
    }
    __syncthreads();

    // ---- GEMM2: x2 = tanh(x1 @ Wa2 + ba2); fused score = x2 @ Wa3 ----
    {
        short8_t ha[4];
        const unsigned short* ar = hmS + (w * 16 + lr) * LDH + lg * 8;
        #pragma unroll
        for (int kk = 0; kk < 4; ++kk) ha[kk] = *(const short8_t*)(ar + kk * 32);
        float p[4] = {0.f, 0.f, 0.f, 0.f};
        #pragma unroll
        for (int n = 0; n < 8; ++n) {
            const unsigned short* br = wbt2 + (n * 16 + lr) * 128 + lg * 8;
            short8_t b0 = *(const short8_t*)(br);
            short8_t b1 = *(const short8_t*)(br + 32);
            short8_t b2 = *(const short8_t*)(br + 64);
            short8_t b3 = *(const short8_t*)(br + 96);
            const float bi = ba2S[n * 16 + lr];
            f32x4 acc = {bi, bi, bi, bi};
            acc = MFMA16(ha[0], b0, acc);
            acc = MFMA16(ha[1], b1, acc);
            acc = MFMA16(ha[2], b2, acc);
            acc = MFMA16(ha[3], b3, acc);
            const float wv = wa3S[n * 16 + lr];
            #pragma unroll
            for (int i = 0; i < 4; ++i)
                p[i] += ftanh(acc[i]) * wv;
        }
        #pragma unroll
        for (int i = 0; i < 4; ++i) {
            float v = p[i];
            v += __shfl_xor(v, 1);
            v += __shfl_xor(v, 2);
            v += __shfl_xor(v, 4);
            v += __shfl_xor(v, 8);
            if (lr == 0) scS[w * 16 + lg * 4 + i] = v;
        }
    }
    __syncthreads();

    // ---- softmax over machines (output 0) ----
    if (tid < G) {
        const int g = tid;
        float sc[NM];
        float mx = -INFINITY;
        #pragma unroll
        for (int m2 = 0; m2 < NM; ++m2) {
            float s = (scS[g * NM + m2] + ba3[0]) * 10.0f;
            if (mask[(size_t)(b0 + g) * NM + m2]) s = -INFINITY;
            sc[m2] = s;
            mx = fmaxf(mx, s);
        }
        float sum = 0.f;
        #pragma unroll
        for (int m2 = 0; m2 < NM; ++m2) {
            float e = __expf(sc[m2] - mx);
            sc[m2] = e;
            sum += e;
        }
        const float inv = 1.0f / sum;
        #pragma unroll
        for (int m2 = 0; m2 < NM; ++m2)
            out[(size_t)(b0 + g) * NM + m2] = sc[m2] * inv;
    }

    // ---- critic (fp32 VALU): v = tanh(hp @ Wc1 + bc1); weight loads hoisted,
    //      both g's per thread accumulate off one Wc load (half the loads, 2x ILP) ----
    {
        const int c = tid & 127;
        const int h = tid >> 7;
        {
            float a0 = bc1[c], a1 = a0;
            for (int k = 0; k < HID; ++k) {
                const float wv = Wc1[(size_t)k * HID + c];
                a0 += hpS[h * HID + k] * wv;
                a1 += hpS[(h + 2) * HID + k] * wv;
            }
            v1S[h * HID + c]       = ftanh(a0);
            v1S[(h + 2) * HID + c] = ftanh(a1);
        }
        __syncthreads();
        {
            float a0 = bc2[c], a1 = a0;
            for (int k = 0; k < HID; ++k) {
                const float wv = Wc2[(size_t)k * HID + c];
                a0 += v1S[h * HID + k] * wv;
                a1 += v1S[(h + 2) * HID + k] * wv;
            }
            v2S[h * HID + c]       = ftanh(a0);
            v2S[(h + 2) * HID + c] = ftanh(a1);
        }
        __syncthreads();
    }

    // ---- machine_v = v2 @ Wc3 + bc3 (output 2) ----
    if (tid < G * 2) {
        const int g = tid >> 1;
        const int o = tid & 1;
        float acc = bc3[o];
        for (int k = 0; k < HID; ++k) acc += v2S[g * HID + k] * Wc3[k * 2 + o];
        out[O2 + (size_t)(b0 + g) * 2 + o] = acc;
    }
}

// ---------------------------------------------------------------------------
extern "C" void kernel_launch(void* const* d_in, const int* in_sizes, int n_in,
                              void* d_out, int out_size, void* d_ws, size_t ws_size,
                              hipStream_t stream)
{
    const float* fea1  = (const float*)d_in[0];
    const float* hpo   = (const float*)d_in[2];
    const unsigned char* mask = (const unsigned char*)d_in[3];
    const float* W1    = (const float*)d_in[4];
    const float* gamma = (const float*)d_in[8];
    const float* beta  = (const float*)d_in[9];
    const float* Wa1   = (const float*)d_in[10];
    const float* ba1   = (const float*)d_in[11];
    const float* Wa2   = (const float*)d_in[12];
    const float* ba2   = (const float*)d_in[13];
    const float* Wa3   = (const float*)d_in[14];
    const float* ba3   = (const float*)d_in[15];
    const float* Wc1   = (const float*)d_in[16];
    const float* bc1   = (const float*)d_in[17];
    const float* Wc2   = (const float*)d_in[18];
    const float* bc2   = (const float*)d_in[19];
    const float* Wc3   = (const float*)d_in[20];
    const float* bc3   = (const float*)d_in[21];

    float* ws = (float*)d_ws;
    unsigned short* wbt = (unsigned short*)(ws + WS_BW);
    float* out = (float*)d_out;

    bn_stats_kernel<<<S1_BLOCKS, 256, 0, stream>>>(fea1, W1, ws);
    bn_finalize_kernel<<<1, 512, 0, stream>>>(gamma, beta, ws);
    prep_kernel<<<128, 256, 0, stream>>>(Wa1, Wa2, wbt);
    main_kernel<<<BATCH / G, 256, 0, stream>>>(
        fea1, hpo, mask, W1, ba1, ba2, Wa3, ba3,
        Wc1, bc1, Wc2, bc2, Wc3, bc3, ws, wbt, out);
}